// Round 1
// baseline (85.497 us; speedup 1.0000x reference)
//
#include <hip/hip_runtime.h>

#define NB 4096
#define NT 2048
#define NP 12

#define RCP(v) __builtin_amdgcn_rcpf(v)

__global__ __launch_bounds__(64, 1) void esrnn_scan(
    const float* __restrict__ x,
    const float* __restrict__ l0,
    const float* __restrict__ b0,
    const float* __restrict__ s0,
    const float* __restrict__ pa,
    const float* __restrict__ pb,
    const float* __restrict__ pp,
    const float* __restrict__ pg,
    float* __restrict__ out)
{
    const int bi = blockIdx.x * 64 + threadIdx.x;

    const float alpha = pa[0], beta = pb[0], phi = pp[0], gamma = pg[0];
    const float k1 = 1.0f - alpha;          // (1-alpha)
    const float c2 = (1.0f - beta) * phi;   // (1-beta)*phi
    const float c3 = 1.0f - gamma;          // (1-gamma)

    const float* __restrict__ xr = x + (size_t)bi * NT;
    float* __restrict__ orow = out + (size_t)bi * NT;

    float ll = l0[bi];
    float bb = b0[bi];

    // Seasonal circular buffer in registers: all indices compile-time constant
    // (12-step unrolled body). RS = reciprocal, computed at production time so
    // rcp latency hides across the 12-step lag.
    float S[NP], RS[NP];
#pragma unroll
    for (int k = 0; k < NP; ++k) {
        S[k] = s0[bi * NP + k];
        RS[k] = RCP(S[k]);
    }

    float4 A0, A1, A2, B0, B1, B2, C0, C1, C2;

#define LOADG(N, g) do { \
    const float4* _p = (const float4*)(xr + 12 * (g)); \
    N##0 = _p[0]; N##1 = _p[1]; N##2 = _p[2]; \
} while (0)

// One recurrence step. j is a literal in [0,12); xt input; od = output dest.
#define STEP(j, xt, od) do { \
    const float sf   = S[(j)]; \
    const float t1   = fmaf(phi, bb, ll); \
    const float lnew = fmaf(k1, t1, alpha * (xt) * RS[(j)]); \
    const float bnew = fmaf(beta, lnew - ll, c2 * bb); \
    const float lb   = fmaf(phi, bnew, lnew); \
    const float snew = fmaf(gamma * (xt), RCP(lb), c3 * sf); \
    (od) = lb * S[((j) + 1) % NP]; \
    S[(j)]  = snew; \
    RS[(j)] = RCP(snew); \
    ll = lnew; bb = bnew; \
} while (0)

// One 12-step group: consumes 3 float4 of x, stores 3 float4 of out.
#define GROUP(Xa, Xb, Xc, tt) do { \
    float4 o; \
    STEP(0, Xa.x, o.x); STEP(1, Xa.y, o.y); STEP(2, Xa.z, o.z); STEP(3, Xa.w, o.w); \
    *(float4*)(orow + (tt)) = o; \
    STEP(4, Xb.x, o.x); STEP(5, Xb.y, o.y); STEP(6, Xb.z, o.z); STEP(7, Xb.w, o.w); \
    *(float4*)(orow + (tt) + 4) = o; \
    STEP(8, Xc.x, o.x); STEP(9, Xc.y, o.y); STEP(10, Xc.z, o.z); STEP(11, Xc.w, o.w); \
    *(float4*)(orow + (tt) + 8) = o; \
} while (0)

    // Software pipeline, prefetch distance 2 groups (24 steps).
    LOADG(A, 0);
    LOADG(B, 1);
    int g = 0;
#pragma unroll 1
    for (int i = 0; i < 56; ++i) {          // groups 0..167
        LOADG(C, g + 2); GROUP(A0, A1, A2, g * 12);
        LOADG(A, g + 3); GROUP(B0, B1, B2, (g + 1) * 12);
        LOADG(B, g + 4); GROUP(C0, C1, C2, (g + 2) * 12);
        g += 3;
    }
    // A = group 168 (t=2016), B = group 169 (t=2028); tail t=2040..2047.
    float4 T0 = *(const float4*)(xr + 2040);
    float4 T1 = *(const float4*)(xr + 2044);
    GROUP(A0, A1, A2, 2016);
    GROUP(B0, B1, B2, 2028);
    {
        float4 o;
        STEP(0, T0.x, o.x); STEP(1, T0.y, o.y); STEP(2, T0.z, o.z); STEP(3, T0.w, o.w);
        *(float4*)(orow + 2040) = o;
        STEP(4, T1.x, o.x); STEP(5, T1.y, o.y); STEP(6, T1.z, o.z); STEP(7, T1.w, o.w);
        *(float4*)(orow + 2044) = o;
    }
#undef LOADG
#undef STEP
#undef GROUP
}

extern "C" void kernel_launch(void* const* d_in, const int* in_sizes, int n_in,
                              void* d_out, int out_size, void* d_ws, size_t ws_size,
                              hipStream_t stream) {
    const float* x  = (const float*)d_in[0];
    const float* l0 = (const float*)d_in[1];
    const float* b0 = (const float*)d_in[2];
    const float* s0 = (const float*)d_in[3];
    const float* pa = (const float*)d_in[4];
    const float* pb = (const float*)d_in[5];
    const float* pp = (const float*)d_in[6];
    const float* pg = (const float*)d_in[7];
    float* out = (float*)d_out;

    esrnn_scan<<<NB / 64, 64, 0, stream>>>(x, l0, b0, s0, pa, pb, pp, pg, out);
}

// Round 2
// 71.725 us; speedup vs baseline: 1.1920x; 1.1920x over previous
//
#include <hip/hip_runtime.h>

#define NB 4096
#define NT 2048
#define NP 12

#define RCP(v) __builtin_amdgcn_rcpf(v)
// Compiler memory barrier: pins global loads issued above it (they cannot
// sink below), preserving the software prefetch pipeline. SSA-promoted
// register arrays (S/RS) are unaffected.
#define MBAR asm volatile("" ::: "memory")

__global__ __launch_bounds__(64, 1) void esrnn_scan(
    const float* __restrict__ x,
    const float* __restrict__ l0,
    const float* __restrict__ b0,
    const float* __restrict__ s0,
    const float* __restrict__ pa,
    const float* __restrict__ pb,
    const float* __restrict__ pp,
    const float* __restrict__ pg,
    float* __restrict__ out)
{
    const int bi = blockIdx.x * 64 + threadIdx.x;

    const float alpha = pa[0], beta = pb[0], phi = pp[0], gamma = pg[0];
    const float k1 = 1.0f - alpha;          // (1-alpha)
    const float c2 = (1.0f - beta) * phi;   // (1-beta)*phi
    const float c3 = 1.0f - gamma;          // (1-gamma)
    const float nbeta = -beta;

    const float* __restrict__ xr = x + (size_t)bi * NT;
    float* __restrict__ orow = out + (size_t)bi * NT;

    float ll = l0[bi];
    float bb = b0[bi];
    float lbv = fmaf(phi, bb, ll);          // carried: l + phi*b

    // Seasonal circular buffer in registers (all indices literal after
    // unroll). RS = reciprocal, produced 12 steps before consumption so
    // v_rcp latency is fully hidden.
    float S[NP], RS[NP];
#pragma unroll
    for (int k = 0; k < NP; ++k) {
        S[k] = s0[bi * NP + k];
        RS[k] = RCP(S[k]);
    }

    float4 A0, A1, A2, B0, B1, B2, C0, C1, C2, D0, D1, D2;

#define LOADG(N, g) do { \
    const float4* _p = (const float4*)(xr + 12 * (g)); \
    N##0 = _p[0]; N##1 = _p[1]; N##2 = _p[2]; \
} while (0)

// One recurrence step. j literal in [0,12). Critical chain: 3 dependent FMAs
// (lnew -> bnew -> lbv); everything else is off-chain filler.
#define STEP(j, xt, od) do { \
    const float axrs = (alpha * (xt)) * RS[(j)]; \
    const float pre  = fmaf(nbeta, ll, c2 * bb); \
    const float lnew = fmaf(k1, lbv, axrs); \
    const float bnew = fmaf(beta, lnew, pre); \
    lbv = fmaf(phi, bnew, lnew); \
    (od) = lbv * S[((j) + 1) % NP]; \
    const float snew = fmaf(gamma * (xt), RCP(lbv), c3 * S[(j)]); \
    S[(j)]  = snew; \
    RS[(j)] = RCP(snew); \
    ll = lnew; bb = bnew; \
} while (0)

// One 12-step group: consumes 3 float4 of x, stores 3 float4 of out.
#define GROUP(Xa, Xb, Xc, tt) do { \
    float4 o; \
    STEP(0, Xa.x, o.x); STEP(1, Xa.y, o.y); STEP(2, Xa.z, o.z); STEP(3, Xa.w, o.w); \
    *(float4*)(orow + (tt)) = o; \
    STEP(4, Xb.x, o.x); STEP(5, Xb.y, o.y); STEP(6, Xb.z, o.z); STEP(7, Xb.w, o.w); \
    *(float4*)(orow + (tt) + 4) = o; \
    STEP(8, Xc.x, o.x); STEP(9, Xc.y, o.y); STEP(10, Xc.z, o.z); STEP(11, Xc.w, o.w); \
    *(float4*)(orow + (tt) + 8) = o; \
} while (0)

    // Software pipeline, prefetch distance 4 groups (48 steps), modulo-4
    // buffer rotation. MBAR after each load cluster pins the loads.
    LOADG(A, 0); LOADG(B, 1); LOADG(C, 2); LOADG(D, 3); MBAR;

#pragma unroll 1
    for (int i = 0; i < 41; ++i) {          // computes groups 0..163
        const int g = i * 4;
        GROUP(A0, A1, A2, g * 12);        LOADG(A, g + 4); MBAR;
        GROUP(B0, B1, B2, (g + 1) * 12);  LOADG(B, g + 5); MBAR;
        GROUP(C0, C1, C2, (g + 2) * 12);  LOADG(C, g + 6); MBAR;
        GROUP(D0, D1, D2, (g + 3) * 12);  LOADG(D, g + 7); MBAR;
    }
    // Buffers now hold groups 164(A), 165(B), 166(C), 167(D).
    float4 T0, T1;
    GROUP(A0, A1, A2, 164 * 12);  LOADG(A, 168); MBAR;
    GROUP(B0, B1, B2, 165 * 12);  LOADG(B, 169);
    T0 = *(const float4*)(xr + 2040);
    T1 = *(const float4*)(xr + 2044);
    MBAR;
    GROUP(C0, C1, C2, 166 * 12);
    GROUP(D0, D1, D2, 167 * 12);
    GROUP(A0, A1, A2, 168 * 12);
    GROUP(B0, B1, B2, 169 * 12);
    {   // tail: t = 2040..2047 (8 steps)
        float4 o;
        STEP(0, T0.x, o.x); STEP(1, T0.y, o.y); STEP(2, T0.z, o.z); STEP(3, T0.w, o.w);
        *(float4*)(orow + 2040) = o;
        STEP(4, T1.x, o.x); STEP(5, T1.y, o.y); STEP(6, T1.z, o.z); STEP(7, T1.w, o.w);
        *(float4*)(orow + 2044) = o;
    }
#undef LOADG
#undef STEP
#undef GROUP
}

extern "C" void kernel_launch(void* const* d_in, const int* in_sizes, int n_in,
                              void* d_out, int out_size, void* d_ws, size_t ws_size,
                              hipStream_t stream) {
    const float* x  = (const float*)d_in[0];
    const float* l0 = (const float*)d_in[1];
    const float* b0 = (const float*)d_in[2];
    const float* s0 = (const float*)d_in[3];
    const float* pa = (const float*)d_in[4];
    const float* pb = (const float*)d_in[5];
    const float* pp = (const float*)d_in[6];
    const float* pg = (const float*)d_in[7];
    float* out = (float*)d_out;

    esrnn_scan<<<NB / 64, 64, 0, stream>>>(x, l0, b0, s0, pa, pb, pp, pg, out);
}